// Round 1
// baseline (174.604 us; speedup 1.0000x reference)
//
#include <hip/hip_runtime.h>
#include <cfloat>

#define B_ 16
#define N_ 4096
#define M_ 1024
#define EPS_ 1e-12f

// ---------------------------------------------------------------------------
// Kernel A: cd1 = sum over (b,n) of min_m dist(pts[b,n], skel[b,m]), scaled 1e-4.
// One block per (b, 256-chunk of n). Skel points for b staged in LDS (12 KB).
// ---------------------------------------------------------------------------
__global__ __launch_bounds__(256) void cd1_kernel(const float* __restrict__ shape_xyz,
                                                  const float* __restrict__ skel_xyz,
                                                  float* __restrict__ out)
{
    __shared__ float sk[M_ * 3];           // 12 KB
    __shared__ float ws[4];

    const int b     = blockIdx.x >> 4;     // N_/256 = 16 chunks
    const int chunk = blockIdx.x & 15;

    const float* skb = skel_xyz + (size_t)b * M_ * 3;
    for (int i = threadIdx.x; i < M_ * 3; i += 256) sk[i] = skb[i];
    __syncthreads();

    const int n = chunk * 256 + threadIdx.x;
    const float* p = shape_xyz + ((size_t)b * N_ + n) * 6;
    const float p0 = p[0], p1 = p[1], p2 = p[2];

    float best = FLT_MAX;
#pragma unroll 8
    for (int m = 0; m < M_; ++m) {
        const float dx = p0 - sk[m * 3 + 0];
        const float dy = p1 - sk[m * 3 + 1];
        const float dz = p2 - sk[m * 3 + 2];
        const float d2 = dx * dx + dy * dy + dz * dz;
        best = fminf(best, d2);
    }
    // sqrt/max are monotone -> apply after the min over squared distances
    float v = sqrtf(fmaxf(best, EPS_)) * 1e-4f;

    // wave reduce (width 64) then cross-wave via LDS
#pragma unroll
    for (int off = 32; off > 0; off >>= 1) v += __shfl_down(v, off);
    if ((threadIdx.x & 63) == 0) ws[threadIdx.x >> 6] = v;
    __syncthreads();
    if (threadIdx.x == 0) atomicAdd(out, ws[0] + ws[1] + ws[2] + ws[3]);
}

// ---------------------------------------------------------------------------
// Kernel B: per (b,m): top-2 nearest n; contributes sqrt(d1)*1e-4 (cd2 part)
// plus 0.001 * mean(|dot(nori, normal[idx_k])|) / B  (normal loss part).
// One block per (b, 64-chunk of m); 4 lanes cooperate per m over strided n.
// All 4096 pts for b staged in LDS (48 KB).
// ---------------------------------------------------------------------------
__global__ __launch_bounds__(256) void knn_kernel(const float* __restrict__ shape_xyz,
                                                  const float* __restrict__ skel_xyz,
                                                  const float* __restrict__ skel_nori,
                                                  float* __restrict__ out)
{
    __shared__ float pts[N_ * 3];          // 48 KB
    __shared__ float ws[4];

    const int b      = blockIdx.x >> 4;    // M_/64 = 16 chunks
    const int mchunk = blockIdx.x & 15;

    const float* sb = shape_xyz + (size_t)b * N_ * 6;
    for (int i = threadIdx.x; i < N_ * 3; i += 256) {
        const int n = i / 3;
        const int c = i - n * 3;
        pts[i] = sb[n * 6 + c];
    }
    __syncthreads();

    const int m   = mchunk * 64 + (threadIdx.x >> 2);
    const int sub = threadIdx.x & 3;

    const float* s = skel_xyz + ((size_t)b * M_ + m) * 3;
    const float s0 = s[0], s1 = s[1], s2 = s[2];

    float d1 = FLT_MAX, d2v = FLT_MAX;     // smallest / second smallest squared dist
    int   i1 = 0,       i2  = 0;

#pragma unroll 4
    for (int n = sub; n < N_; n += 4) {
        const float dx = s0 - pts[n * 3 + 0];
        const float dy = s1 - pts[n * 3 + 1];
        const float dz = s2 - pts[n * 3 + 2];
        const float dd = dx * dx + dy * dy + dz * dz;
        const bool lt1 = dd < d1;
        const bool lt2 = dd < d2v;
        const float nd2 = lt1 ? d1 : (lt2 ? dd : d2v);
        const int   ni2 = lt1 ? i1 : (lt2 ? n : i2);
        d2v = nd2; i2 = ni2;
        d1  = lt1 ? dd : d1;
        i1  = lt1 ? n  : i1;
    }

    // merge top-2 across the 4 cooperating lanes (wave-contiguous -> shfl_xor)
#pragma unroll
    for (int off = 1; off <= 2; off <<= 1) {
        const float o1  = __shfl_xor(d1,  off);
        const int   oi1 = __shfl_xor(i1,  off);
        const float o2  = __shfl_xor(d2v, off);
        const int   oi2 = __shfl_xor(i2,  off);
        const bool ofirst = o1 < d1;
        const float big  = ofirst ? d1 : o1;
        const int   bigi = ofirst ? i1 : oi1;
        const float m1   = ofirst ? o1  : d1;
        const int   mi1  = ofirst ? oi1 : i1;
        const bool osec  = o2 < d2v;
        const float c2   = osec ? o2  : d2v;
        const int   ci2  = osec ? oi2 : i2;
        const bool csec  = c2 < big;
        d1  = m1;  i1 = mi1;
        d2v = csec ? c2  : big;
        i2  = csec ? ci2 : bigi;
    }

    float contrib = 0.0f;
    if (sub == 0) {
        const float* no = skel_nori + ((size_t)b * M_ + m) * 3;
        const float q0 = no[0], q1 = no[1], q2 = no[2];
        const float* nr1 = sb + (size_t)i1 * 6 + 3;
        const float* nr2 = sb + (size_t)i2 * 6 + 3;
        const float dot1 = q0 * nr1[0] + q1 * nr1[1] + q2 * nr1[2];
        const float dot2 = q0 * nr2[0] + q1 * nr2[1] + q2 * nr2[2];
        contrib = sqrtf(fmaxf(d1, EPS_)) * 1e-4f
                + (fabsf(dot1) + fabsf(dot2)) * (0.001f * 0.5f / (float)B_);
    }

#pragma unroll
    for (int off = 32; off > 0; off >>= 1) contrib += __shfl_down(contrib, off);
    if ((threadIdx.x & 63) == 0) ws[threadIdx.x >> 6] = contrib;
    __syncthreads();
    if (threadIdx.x == 0) atomicAdd(out, ws[0] + ws[1] + ws[2] + ws[3]);
}

extern "C" void kernel_launch(void* const* d_in, const int* in_sizes, int n_in,
                              void* d_out, int out_size, void* d_ws, size_t ws_size,
                              hipStream_t stream) {
    const float* shape_xyz = (const float*)d_in[0];  // (16, 4096, 6)
    const float* skel_xyz  = (const float*)d_in[1];  // (16, 1024, 3)
    const float* skel_nori = (const float*)d_in[2];  // (16, 1024, 3)
    float* out = (float*)d_out;                      // scalar

    // d_out is poisoned 0xAA before every timed launch -> zero it ourselves.
    hipMemsetAsync(out, 0, sizeof(float), stream);

    cd1_kernel<<<B_ * (N_ / 256), 256, 0, stream>>>(shape_xyz, skel_xyz, out);
    knn_kernel<<<B_ * (M_ / 64), 256, 0, stream>>>(shape_xyz, skel_xyz, skel_nori, out);
}

// Round 2
// 110.669 us; speedup vs baseline: 1.5777x; 1.5777x over previous
//
#include <hip/hip_runtime.h>
#include <cfloat>

#define B_ 16
#define N_ 4096
#define M_ 1024
#define EPS_ 1e-12f

// ---------------------------------------------------------------------------
// Kernel A: cd1 = sum over (b,n) of min_m dist(pts[b,n], skel[b,m]) * 1e-4.
// 1024 blocks = 16 b x 64 chunks of 64 n. Thread layout: s = tid&15 handles
// m = j*16+s (interleaved -> LDS banks s*3 mod 32, conflict-free), g = tid>>4
// handles 4 points. Min-merge across the 16 s-lanes via shfl_xor.
// ---------------------------------------------------------------------------
__global__ __launch_bounds__(256) void cd1_kernel(const float* __restrict__ shape_xyz,
                                                  const float* __restrict__ skel_xyz,
                                                  float* __restrict__ out)
{
    __shared__ float sk[M_ * 3];           // 12 KB
    __shared__ float ws[4];

    const int b     = blockIdx.x >> 6;     // 64 chunks per b
    const int chunk = blockIdx.x & 63;

    const float* skb = skel_xyz + (size_t)b * M_ * 3;
    for (int i = threadIdx.x; i < M_ * 3; i += 256) sk[i] = skb[i];
    __syncthreads();

    const int s = threadIdx.x & 15;        // m-split
    const int g = threadIdx.x >> 4;        // point group (16 groups x 4 pts)
    const int nb = chunk * 64 + g * 4;

    const float* p = shape_xyz + ((size_t)b * N_ + nb) * 6;
    float px[4], py[4], pz[4];
#pragma unroll
    for (int k = 0; k < 4; ++k) {
        px[k] = p[k * 6 + 0]; py[k] = p[k * 6 + 1]; pz[k] = p[k * 6 + 2];
    }

    float best[4] = {FLT_MAX, FLT_MAX, FLT_MAX, FLT_MAX};
#pragma unroll 4
    for (int j = 0; j < M_ / 16; ++j) {
        const int m = j * 16 + s;
        const float sx = sk[m * 3 + 0];
        const float sy = sk[m * 3 + 1];
        const float sz = sk[m * 3 + 2];
#pragma unroll
        for (int k = 0; k < 4; ++k) {
            const float dx = px[k] - sx;
            const float dy = py[k] - sy;
            const float dz = pz[k] - sz;
            best[k] = fminf(best[k], dx * dx + dy * dy + dz * dz);
        }
    }

    // min across the 16 s-lanes (contiguous within the wave)
#pragma unroll
    for (int off = 1; off < 16; off <<= 1) {
#pragma unroll
        for (int k = 0; k < 4; ++k) best[k] = fminf(best[k], __shfl_xor(best[k], off));
    }

    float v = 0.0f;
    if (s == 0) {
#pragma unroll
        for (int k = 0; k < 4; ++k) v += sqrtf(fmaxf(best[k], EPS_));
        v *= 1e-4f;
    }
#pragma unroll
    for (int off = 32; off > 0; off >>= 1) v += __shfl_down(v, off);
    if ((threadIdx.x & 63) == 0) ws[threadIdx.x >> 6] = v;
    __syncthreads();
    if (threadIdx.x == 0) atomicAdd(out, ws[0] + ws[1] + ws[2] + ws[3]);
}

// ---------------------------------------------------------------------------
// Kernel B: per (b,m): top-2 nearest n; contributes sqrt(d1)*1e-4 (cd2 part)
// plus 0.001/2/B * (|dot1|+|dot2|) (normal loss part).
// 1024 blocks = 16 b x 64 chunks of 16 m. Thread layout: s = tid&31 scans
// n = j*32+s (interleaved, conflict-free), g = tid>>5 handles 2 skel points.
// Butterfly top-2 merge across the 32 s-lanes.
// ---------------------------------------------------------------------------
__global__ __launch_bounds__(256) void knn_kernel(const float* __restrict__ shape_xyz,
                                                  const float* __restrict__ skel_xyz,
                                                  const float* __restrict__ skel_nori,
                                                  float* __restrict__ out)
{
    __shared__ float pts[N_ * 3];          // 48 KB
    __shared__ float ws[4];

    const int b      = blockIdx.x >> 6;    // 64 chunks per b
    const int mchunk = blockIdx.x & 63;

    const float* sb = shape_xyz + (size_t)b * N_ * 6;
    for (int n = threadIdx.x; n < N_; n += 256) {
        pts[n * 3 + 0] = sb[n * 6 + 0];
        pts[n * 3 + 1] = sb[n * 6 + 1];
        pts[n * 3 + 2] = sb[n * 6 + 2];
    }
    __syncthreads();

    const int s  = threadIdx.x & 31;       // n-split
    const int g  = threadIdx.x >> 5;       // 0..7, 2 m each
    const int m0 = mchunk * 16 + g * 2;

    const float* sq = skel_xyz + ((size_t)b * M_ + m0) * 3;
    const float ax = sq[0], ay = sq[1], az = sq[2];
    const float bx = sq[3], by = sq[4], bz = sq[5];

    float a1 = FLT_MAX, a2 = FLT_MAX, c1 = FLT_MAX, c2 = FLT_MAX;
    int   ai1 = 0, ai2 = 0, ci1 = 0, ci2 = 0;

#pragma unroll 4
    for (int j = 0; j < N_ / 32; ++j) {
        const int n = j * 32 + s;
        const float qx = pts[n * 3 + 0];
        const float qy = pts[n * 3 + 1];
        const float qz = pts[n * 3 + 2];
        {
            const float dx = ax - qx, dy = ay - qy, dz = az - qz;
            const float dd = dx * dx + dy * dy + dz * dz;
            const bool lt1 = dd < a1, lt2 = dd < a2;
            a2  = lt1 ? a1  : (lt2 ? dd : a2);
            ai2 = lt1 ? ai1 : (lt2 ? n  : ai2);
            a1  = lt1 ? dd : a1;
            ai1 = lt1 ? n  : ai1;
        }
        {
            const float dx = bx - qx, dy = by - qy, dz = bz - qz;
            const float dd = dx * dx + dy * dy + dz * dz;
            const bool lt1 = dd < c1, lt2 = dd < c2;
            c2  = lt1 ? c1  : (lt2 ? dd : c2);
            ci2 = lt1 ? ci1 : (lt2 ? n  : ci2);
            c1  = lt1 ? dd : c1;
            ci1 = lt1 ? n  : ci1;
        }
    }

    // butterfly top-2 merge across 32 s-lanes: merged = {min(a1,b1),
    // min(max(a1,b1), min(a2,b2))}
#pragma unroll
    for (int off = 1; off < 32; off <<= 1) {
        {
            const float o1 = __shfl_xor(a1, off); const int oi1 = __shfl_xor(ai1, off);
            const float o2 = __shfl_xor(a2, off); const int oi2 = __shfl_xor(ai2, off);
            const bool  of   = o1 < a1;
            const float big  = of ? a1  : o1;  const int bigi = of ? ai1 : oi1;
            const float m1   = of ? o1  : a1;  const int mi1  = of ? oi1 : ai1;
            const bool  os   = o2 < a2;
            const float sec  = os ? o2  : a2;  const int seci = os ? oi2 : ai2;
            const bool  cs   = sec < big;
            a1 = m1; ai1 = mi1;
            a2 = cs ? sec : big; ai2 = cs ? seci : bigi;
        }
        {
            const float o1 = __shfl_xor(c1, off); const int oi1 = __shfl_xor(ci1, off);
            const float o2 = __shfl_xor(c2, off); const int oi2 = __shfl_xor(ci2, off);
            const bool  of   = o1 < c1;
            const float big  = of ? c1  : o1;  const int bigi = of ? ci1 : oi1;
            const float m1   = of ? o1  : c1;  const int mi1  = of ? oi1 : ci1;
            const bool  os   = o2 < c2;
            const float sec  = os ? o2  : c2;  const int seci = os ? oi2 : ci2;
            const bool  cs   = sec < big;
            c1 = m1; ci1 = mi1;
            c2 = cs ? sec : big; ci2 = cs ? seci : bigi;
        }
    }

    float contrib = 0.0f;
    if (s == 0) {
        const float* no = skel_nori + ((size_t)b * M_ + m0) * 3;
        const float q0 = no[0], q1 = no[1], q2 = no[2];
        const float q3 = no[3], q4 = no[4], q5 = no[5];
        const float* na1 = sb + (size_t)ai1 * 6 + 3;
        const float* na2 = sb + (size_t)ai2 * 6 + 3;
        const float* nc1 = sb + (size_t)ci1 * 6 + 3;
        const float* nc2 = sb + (size_t)ci2 * 6 + 3;
        const float dotA1 = q0 * na1[0] + q1 * na1[1] + q2 * na1[2];
        const float dotA2 = q0 * na2[0] + q1 * na2[1] + q2 * na2[2];
        const float dotC1 = q3 * nc1[0] + q4 * nc1[1] + q5 * nc1[2];
        const float dotC2 = q3 * nc2[0] + q4 * nc2[1] + q5 * nc2[2];
        const float kN = 0.001f * 0.5f / (float)B_;
        contrib = (sqrtf(fmaxf(a1, EPS_)) + sqrtf(fmaxf(c1, EPS_))) * 1e-4f
                + (fabsf(dotA1) + fabsf(dotA2) + fabsf(dotC1) + fabsf(dotC2)) * kN;
    }

#pragma unroll
    for (int off = 32; off > 0; off >>= 1) contrib += __shfl_down(contrib, off);
    if ((threadIdx.x & 63) == 0) ws[threadIdx.x >> 6] = contrib;
    __syncthreads();
    if (threadIdx.x == 0) atomicAdd(out, ws[0] + ws[1] + ws[2] + ws[3]);
}

extern "C" void kernel_launch(void* const* d_in, const int* in_sizes, int n_in,
                              void* d_out, int out_size, void* d_ws, size_t ws_size,
                              hipStream_t stream) {
    const float* shape_xyz = (const float*)d_in[0];  // (16, 4096, 6)
    const float* skel_xyz  = (const float*)d_in[1];  // (16, 1024, 3)
    const float* skel_nori = (const float*)d_in[2];  // (16, 1024, 3)
    float* out = (float*)d_out;                      // scalar

    // d_out is poisoned 0xAA before every timed launch -> zero it ourselves.
    hipMemsetAsync(out, 0, sizeof(float), stream);

    cd1_kernel<<<B_ * 64, 256, 0, stream>>>(shape_xyz, skel_xyz, out);
    knn_kernel<<<B_ * 64, 256, 0, stream>>>(shape_xyz, skel_xyz, skel_nori, out);
}

// Round 3
// 109.221 us; speedup vs baseline: 1.5986x; 1.0133x over previous
//
#include <hip/hip_runtime.h>
#include <cfloat>

#define B_ 16
#define N_ 4096
#define M_ 1024
#define EPS_ 1e-12f

// One fused kernel, 2048 blocks. role = blockIdx&1:
//   role 0 (1024 blocks): cd1 = sum_{b,n} min_m dist * 1e-4.
//     Layout: s=tid&15 owns m=j*16+s, g=tid>>4 owns 4 points. Per-pair core is
//     3 FMAs on t = |s|^2 - 2 p.s (|p|^2 added after the min; monotone).
//     LDS: skel SoA x/y/z/|s|^2 = 16 KB.
//   role 1 (1024 blocks): per (b,m) top-2 over n -> cd2 + normal loss.
//     Layout: s=tid&31 scans n=j*32+s, g=tid>>5 owns 2 m-chains. Per-pair core
//     is 3 FMAs on t = |q|^2 - 2 a.q (|a|^2 constant per chain; exact index
//     tracking via cmp/cndmask; distances via min/max). LDS: pts SoA staged in
//     two 2048-point phases = 24 KB -> 6 blocks/CU residency.
__global__ __launch_bounds__(256) void fused_kernel(const float* __restrict__ shape_xyz,
                                                    const float* __restrict__ skel_xyz,
                                                    const float* __restrict__ skel_nori,
                                                    float* __restrict__ out)
{
    __shared__ float ls[6144];   // 24 KB, role-dependent layout
    __shared__ float ws[4];

    const int role = blockIdx.x & 1;
    const int id   = blockIdx.x >> 1;      // 0..1023
    const int b    = id >> 6;
    const int sub  = id & 63;

    float v = 0.0f;                        // this thread's contribution

    if (role == 0) {
        // ----------------- cd1 -----------------
        const float* skb = skel_xyz + (size_t)b * M_ * 3;
        for (int i = threadIdx.x; i < M_; i += 256) {
            const float x = skb[i * 3 + 0];
            const float y = skb[i * 3 + 1];
            const float z = skb[i * 3 + 2];
            ls[i]          = x;
            ls[1024 + i]   = y;
            ls[2048 + i]   = z;
            ls[3072 + i]   = x * x + y * y + z * z;   // |s|^2
        }
        __syncthreads();

        const int s  = threadIdx.x & 15;
        const int g  = threadIdx.x >> 4;
        const int n0 = sub * 64 + g * 4;

        const float* p = shape_xyz + ((size_t)b * N_ + n0) * 6;
        float m2x[4], m2y[4], m2z[4], pp[4], best[4];
#pragma unroll
        for (int k = 0; k < 4; ++k) {
            const float x = p[k * 6 + 0];
            const float y = p[k * 6 + 1];
            const float z = p[k * 6 + 2];
            m2x[k] = -2.0f * x; m2y[k] = -2.0f * y; m2z[k] = -2.0f * z;
            pp[k]  = x * x + y * y + z * z;           // |p|^2
            best[k] = FLT_MAX;
        }

#pragma unroll 4
        for (int j = 0; j < M_ / 16; ++j) {
            const int m = j * 16 + s;
            const float sx = ls[m];
            const float sy = ls[1024 + m];
            const float sz = ls[2048 + m];
            const float h  = ls[3072 + m];
#pragma unroll
            for (int k = 0; k < 4; ++k) {
                const float t = fmaf(m2x[k], sx, fmaf(m2y[k], sy, fmaf(m2z[k], sz, h)));
                best[k] = fminf(best[k], t);
            }
        }

        // min across the 16 s-lanes (xor < 16 stays within the group)
#pragma unroll
        for (int off = 1; off < 16; off <<= 1) {
#pragma unroll
            for (int k = 0; k < 4; ++k) best[k] = fminf(best[k], __shfl_xor(best[k], off));
        }
        if (s == 0) {
#pragma unroll
            for (int k = 0; k < 4; ++k) v += sqrtf(fmaxf(best[k] + pp[k], EPS_));
            v *= 1e-4f;
        }
    } else {
        // ----------------- knn (cd2 + normal loss) -----------------
        const int s  = threadIdx.x & 31;
        const int g  = threadIdx.x >> 5;           // 0..7
        const int m0 = sub * 16 + g * 2;

        const float* sq = skel_xyz + ((size_t)b * M_ + m0) * 3;
        const float ax = sq[0], ay = sq[1], az = sq[2];
        const float cx = sq[3], cy = sq[4], cz = sq[5];
        const float m2ax = -2.0f * ax, m2ay = -2.0f * ay, m2az = -2.0f * az;
        const float m2cx = -2.0f * cx, m2cy = -2.0f * cy, m2cz = -2.0f * cz;
        const float aa = ax * ax + ay * ay + az * az;
        const float cc = cx * cx + cy * cy + cz * cz;

        float k1a = FLT_MAX, k2a = FLT_MAX, k1c = FLT_MAX, k2c = FLT_MAX;
        int   i1a = 0, i2a = 0, i1c = 0, i2c = 0;

        const float* sb = shape_xyz + (size_t)b * N_ * 6;

        for (int ph = 0; ph < 2; ++ph) {
            __syncthreads();                       // previous phase fully read
            for (int i = threadIdx.x; i < 2048; i += 256) {
                const float* pt = sb + (size_t)(ph * 2048 + i) * 6;
                ls[i]        = pt[0];
                ls[2048 + i] = pt[1];
                ls[4096 + i] = pt[2];
            }
            __syncthreads();
            const int nb = ph * 2048;

#pragma unroll 4
            for (int j = 0; j < 64; ++j) {
                const int n = j * 32 + s;
                const float qx = ls[n];
                const float qy = ls[2048 + n];
                const float qz = ls[4096 + n];
                float q2 = qx * qx; q2 = fmaf(qy, qy, q2); q2 = fmaf(qz, qz, q2);
                const int gn = nb + n;
                {
                    const float t = fmaf(m2ax, qx, fmaf(m2ay, qy, fmaf(m2az, qz, q2)));
                    const bool lt1 = t < k1a, lt2 = t < k2a;
                    i2a = lt1 ? i1a : (lt2 ? gn : i2a);
                    i1a = lt1 ? gn : i1a;
                    k2a = fminf(fmaxf(t, k1a), k2a);
                    k1a = fminf(t, k1a);
                }
                {
                    const float t = fmaf(m2cx, qx, fmaf(m2cy, qy, fmaf(m2cz, qz, q2)));
                    const bool lt1 = t < k1c, lt2 = t < k2c;
                    i2c = lt1 ? i1c : (lt2 ? gn : i2c);
                    i1c = lt1 ? gn : i1c;
                    k2c = fminf(fmaxf(t, k1c), k2c);
                    k1c = fminf(t, k1c);
                }
            }
        }

        // butterfly top-2 merge across the 32 s-lanes
#pragma unroll
        for (int off = 1; off < 32; off <<= 1) {
            {
                const float o1 = __shfl_xor(k1a, off); const int oi1 = __shfl_xor(i1a, off);
                const float o2 = __shfl_xor(k2a, off); const int oi2 = __shfl_xor(i2a, off);
                const bool  of = o1 < k1a;
                const float big = of ? k1a : o1;  const int bigi = of ? i1a : oi1;
                const float n1  = of ? o1 : k1a;  const int ni1  = of ? oi1 : i1a;
                const bool  os = o2 < k2a;
                const float c2v = os ? o2 : k2a;  const int ci2  = os ? oi2 : i2a;
                const bool  cs = c2v < big;
                k1a = n1; i1a = ni1;
                k2a = cs ? c2v : big; i2a = cs ? ci2 : bigi;
            }
            {
                const float o1 = __shfl_xor(k1c, off); const int oi1 = __shfl_xor(i1c, off);
                const float o2 = __shfl_xor(k2c, off); const int oi2 = __shfl_xor(i2c, off);
                const bool  of = o1 < k1c;
                const float big = of ? k1c : o1;  const int bigi = of ? i1c : oi1;
                const float n1  = of ? o1 : k1c;  const int ni1  = of ? oi1 : i1c;
                const bool  os = o2 < k2c;
                const float c2v = os ? o2 : k2c;  const int ci2  = os ? oi2 : i2c;
                const bool  cs = c2v < big;
                k1c = n1; i1c = ni1;
                k2c = cs ? c2v : big; i2c = cs ? ci2 : bigi;
            }
        }

        if (s == 0) {
            const float* no = skel_nori + ((size_t)b * M_ + m0) * 3;
            const float q0 = no[0], q1 = no[1], q2n = no[2];
            const float q3 = no[3], q4 = no[4], q5 = no[5];
            const float* na1 = sb + (size_t)i1a * 6 + 3;
            const float* na2 = sb + (size_t)i2a * 6 + 3;
            const float* nc1 = sb + (size_t)i1c * 6 + 3;
            const float* nc2 = sb + (size_t)i2c * 6 + 3;
            const float dA1 = q0 * na1[0] + q1 * na1[1] + q2n * na1[2];
            const float dA2 = q0 * na2[0] + q1 * na2[1] + q2n * na2[2];
            const float dC1 = q3 * nc1[0] + q4 * nc1[1] + q5 * nc1[2];
            const float dC2 = q3 * nc2[0] + q4 * nc2[1] + q5 * nc2[2];
            const float kN = 0.001f * 0.5f / (float)B_;
            v = (sqrtf(fmaxf(k1a + aa, EPS_)) + sqrtf(fmaxf(k1c + cc, EPS_))) * 1e-4f
              + (fabsf(dA1) + fabsf(dA2) + fabsf(dC1) + fabsf(dC2)) * kN;
        }
    }

    // common block reduction + one atomic per block
#pragma unroll
    for (int off = 32; off > 0; off >>= 1) v += __shfl_down(v, off);
    if ((threadIdx.x & 63) == 0) ws[threadIdx.x >> 6] = v;
    __syncthreads();
    if (threadIdx.x == 0) atomicAdd(out, ws[0] + ws[1] + ws[2] + ws[3]);
}

extern "C" void kernel_launch(void* const* d_in, const int* in_sizes, int n_in,
                              void* d_out, int out_size, void* d_ws, size_t ws_size,
                              hipStream_t stream) {
    const float* shape_xyz = (const float*)d_in[0];  // (16, 4096, 6)
    const float* skel_xyz  = (const float*)d_in[1];  // (16, 1024, 3)
    const float* skel_nori = (const float*)d_in[2];  // (16, 1024, 3)
    float* out = (float*)d_out;                      // scalar

    hipMemsetAsync(out, 0, sizeof(float), stream);   // d_out poisoned each call
    fused_kernel<<<2048, 256, 0, stream>>>(shape_xyz, skel_xyz, skel_nori, out);
}

// Round 4
// 90.915 us; speedup vs baseline: 1.9205x; 1.2014x over previous
//
#include <hip/hip_runtime.h>
#include <cfloat>
#include <stdint.h>

#define B_ 16
#define N_ 4096
#define M_ 1024
#define EPS_ 1e-12f

// Fused kernel, 2048 blocks, role = blockIdx&1.
// role 0 (cd1): s=tid&15 owns m=j*16+s, g=tid>>4 owns 4 points.
//   LDS: skel as float4[x,y,z,|s|^2] (16 KB). Per pair: 3 fma + 1 min.
// role 1 (knn -> cd2 + normal loss): s=tid&31 scans n=j*32+s, g=tid>>5 owns
//   2 m-chains. LDS: pts as float4[x,y,z,|q|^2], staged in 4x1024 phases
//   (16 KB). Per pair: 1 add + 3 fma + 1 and_or + 3 u32 min/max on a packed
//   key = (bits(d^2) & ~0xFFF) | n  (d^2 >= 0 so uint order == float order;
//   low-12-bit index breaks ties toward smaller n like top_k). Exact
//   distances recomputed for the 2 winners in the epilogue.
__global__ __launch_bounds__(256, 8) void fused_kernel(const float* __restrict__ shape_xyz,
                                                       const float* __restrict__ skel_xyz,
                                                       const float* __restrict__ skel_nori,
                                                       float* __restrict__ out)
{
    __shared__ float4 ls4[1024];   // 16 KB
    __shared__ float ws[4];

    const int role = blockIdx.x & 1;
    const int id   = blockIdx.x >> 1;      // 0..1023
    const int b    = id >> 6;
    const int sub  = id & 63;

    float v = 0.0f;

    if (role == 0) {
        // ----------------- cd1 -----------------
        const float* skb = skel_xyz + (size_t)b * M_ * 3;
        for (int i = threadIdx.x; i < M_; i += 256) {
            const float x = skb[i * 3 + 0];
            const float y = skb[i * 3 + 1];
            const float z = skb[i * 3 + 2];
            ls4[i] = make_float4(x, y, z, fmaf(x, x, fmaf(y, y, z * z)));
        }
        __syncthreads();

        const int s  = threadIdx.x & 15;
        const int g  = threadIdx.x >> 4;
        const int n0 = sub * 64 + g * 4;

        const float* p = shape_xyz + ((size_t)b * N_ + n0) * 6;
        float m2x[4], m2y[4], m2z[4], pp[4], best[4];
#pragma unroll
        for (int k = 0; k < 4; ++k) {
            const float x = p[k * 6 + 0];
            const float y = p[k * 6 + 1];
            const float z = p[k * 6 + 2];
            m2x[k] = -2.0f * x; m2y[k] = -2.0f * y; m2z[k] = -2.0f * z;
            pp[k]  = fmaf(x, x, fmaf(y, y, z * z));
            best[k] = FLT_MAX;
        }

#pragma unroll 4
        for (int j = 0; j < M_ / 16; ++j) {
            const float4 sv = ls4[j * 16 + s];
#pragma unroll
            for (int k = 0; k < 4; ++k) {
                const float t = fmaf(m2x[k], sv.x, fmaf(m2y[k], sv.y, fmaf(m2z[k], sv.z, sv.w)));
                best[k] = fminf(best[k], t);
            }
        }

#pragma unroll
        for (int off = 1; off < 16; off <<= 1) {
#pragma unroll
            for (int k = 0; k < 4; ++k) best[k] = fminf(best[k], __shfl_xor(best[k], off));
        }
        if (s == 0) {
#pragma unroll
            for (int k = 0; k < 4; ++k) v += sqrtf(fmaxf(best[k] + pp[k], EPS_));
            v *= 1e-4f;
        }
    } else {
        // ----------------- knn (cd2 + normal loss) -----------------
        const int s  = threadIdx.x & 31;
        const int g  = threadIdx.x >> 5;           // 0..7
        const int m0 = sub * 16 + g * 2;

        const float* sq = skel_xyz + ((size_t)b * M_ + m0) * 3;
        const float ax = sq[0], ay = sq[1], az = sq[2];
        const float cx = sq[3], cy = sq[4], cz = sq[5];
        const float m2ax = -2.0f * ax, m2ay = -2.0f * ay, m2az = -2.0f * az;
        const float m2cx = -2.0f * cx, m2cy = -2.0f * cy, m2cz = -2.0f * cz;
        const float aa = fmaf(ax, ax, fmaf(ay, ay, az * az));
        const float cc = fmaf(cx, cx, fmaf(cy, cy, cz * cz));

        const uint32_t HI = 0xFFFFF000u;
        uint32_t k1a = 0xFFFFFFFFu, k2a = 0xFFFFFFFFu;
        uint32_t k1c = 0xFFFFFFFFu, k2c = 0xFFFFFFFFu;

        const float* sb = shape_xyz + (size_t)b * N_ * 6;

        for (int ph = 0; ph < 4; ++ph) {
            __syncthreads();                       // previous phase fully read
            for (int i = threadIdx.x; i < 1024; i += 256) {
                const float* pt = sb + (size_t)(ph * 1024 + i) * 6;
                const float x = pt[0], y = pt[1], z = pt[2];
                ls4[i] = make_float4(x, y, z, fmaf(x, x, fmaf(y, y, z * z)));
            }
            __syncthreads();
            const uint32_t nb = ph * 1024;

#pragma unroll 4
            for (int j = 0; j < 32; ++j) {
                const int nl = j * 32 + s;
                const float4 q = ls4[nl];
                const uint32_t gn = nb + (uint32_t)nl;
                {
                    const float h = q.w + aa;      // makes t = d^2 >= 0
                    const float t = fmaf(m2ax, q.x, fmaf(m2ay, q.y, fmaf(m2az, q.z, h)));
                    const uint32_t key = (__float_as_uint(t) & HI) | gn;
                    k2a = min(max(key, k1a), k2a);
                    k1a = min(key, k1a);
                }
                {
                    const float h = q.w + cc;
                    const float t = fmaf(m2cx, q.x, fmaf(m2cy, q.y, fmaf(m2cz, q.z, h)));
                    const uint32_t key = (__float_as_uint(t) & HI) | gn;
                    k2c = min(max(key, k1c), k2c);
                    k1c = min(key, k1c);
                }
            }
        }

        // butterfly top-2 merge across the 32 s-lanes (packed keys)
#pragma unroll
        for (int off = 1; off < 32; off <<= 1) {
            {
                const uint32_t o1 = (uint32_t)__shfl_xor((int)k1a, off);
                const uint32_t o2 = (uint32_t)__shfl_xor((int)k2a, off);
                const uint32_t nk2 = min(min(k2a, o2), max(k1a, o1));
                k1a = min(k1a, o1);
                k2a = nk2;
            }
            {
                const uint32_t o1 = (uint32_t)__shfl_xor((int)k1c, off);
                const uint32_t o2 = (uint32_t)__shfl_xor((int)k2c, off);
                const uint32_t nk2 = min(min(k2c, o2), max(k1c, o1));
                k1c = min(k1c, o1);
                k2c = nk2;
            }
        }

        if (s == 0) {
            const int i1a = (int)(k1a & 0xFFFu), i2a = (int)(k2a & 0xFFFu);
            const int i1c = (int)(k1c & 0xFFFu), i2c = (int)(k2c & 0xFFFu);
            const float* no = skel_nori + ((size_t)b * M_ + m0) * 3;
            const float q0 = no[0], q1 = no[1], q2n = no[2];
            const float q3 = no[3], q4 = no[4], q5 = no[5];
            const float* pa1 = sb + (size_t)i1a * 6;
            const float* pa2 = sb + (size_t)i2a * 6;
            const float* pc1 = sb + (size_t)i1c * 6;
            const float* pc2 = sb + (size_t)i2c * 6;
            // exact nearest distances (removes key quantization from cd2)
            const float dax = ax - pa1[0], day = ay - pa1[1], daz = az - pa1[2];
            const float dcx = cx - pc1[0], dcy = cy - pc1[1], dcz = cz - pc1[2];
            const float d2a = fmaf(dax, dax, fmaf(day, day, daz * daz));
            const float d2c = fmaf(dcx, dcx, fmaf(dcy, dcy, dcz * dcz));
            const float dA1 = q0 * pa1[3] + q1 * pa1[4] + q2n * pa1[5];
            const float dA2 = q0 * pa2[3] + q1 * pa2[4] + q2n * pa2[5];
            const float dC1 = q3 * pc1[3] + q4 * pc1[4] + q5 * pc1[5];
            const float dC2 = q3 * pc2[3] + q4 * pc2[4] + q5 * pc2[5];
            const float kN = 0.001f * 0.5f / (float)B_;
            v = (sqrtf(fmaxf(d2a, EPS_)) + sqrtf(fmaxf(d2c, EPS_))) * 1e-4f
              + (fabsf(dA1) + fabsf(dA2) + fabsf(dC1) + fabsf(dC2)) * kN;
        }
    }

    // block reduction + one atomic per block
#pragma unroll
    for (int off = 32; off > 0; off >>= 1) v += __shfl_down(v, off);
    if ((threadIdx.x & 63) == 0) ws[threadIdx.x >> 6] = v;
    __syncthreads();
    if (threadIdx.x == 0) atomicAdd(out, ws[0] + ws[1] + ws[2] + ws[3]);
}

extern "C" void kernel_launch(void* const* d_in, const int* in_sizes, int n_in,
                              void* d_out, int out_size, void* d_ws, size_t ws_size,
                              hipStream_t stream) {
    const float* shape_xyz = (const float*)d_in[0];  // (16, 4096, 6)
    const float* skel_xyz  = (const float*)d_in[1];  // (16, 1024, 3)
    const float* skel_nori = (const float*)d_in[2];  // (16, 1024, 3)
    float* out = (float*)d_out;                      // scalar

    hipMemsetAsync(out, 0, sizeof(float), stream);   // d_out poisoned each call
    fused_kernel<<<2048, 256, 0, stream>>>(shape_xyz, skel_xyz, skel_nori, out);
}